// Round 8
// baseline (176.420 us; speedup 1.0000x reference)
//
#include <hip/hip_runtime.h>
#include <hip/hip_bf16.h>

// ---- problem constants ----
#define NN 25000
#define PP 100000
#define TT 4
#define DD 128
#define LEAKY 0.001f

#define PB 32          // propers per block (4 waves x 8 propers)
#define WPB 4          // waves per block
#define PPW 8          // propers per wave
#define RPW 32         // rows per wave (2 M-tiles of 16)

typedef __bf16 bf16;
typedef __bf16 bf16x8 __attribute__((ext_vector_type(8)));
typedef float  f32x4  __attribute__((ext_vector_type(4)));
typedef float  f32x2  __attribute__((ext_vector_type(2)));

// ---- workspace layout (bytes) ----
#define OFF_W0SW  0u                    // 128 chunks * 1KB (fragment order)
#define OFF_W1SW  131072u               // 32 chunks * 1KB
#define OFF_W2SW  163840u               // 32 chunks * 1KB
#define OFF_W3SW  196608u               // 4 chunks * 1KB
#define OFF_WTB   200704u               // Wt[t][j] = t*W0[512]+b0, 4*128 bf16
#define OFF_W5B   201728u               // W0 rows 513..515 as bf16
#define OFF_E     202496u               // 4 tables [NN][128] bf16 = 25,600,000 B
#define WS_END    25802496u

// prep work partition (thread counts)
#define PR_W0SW  8192
#define PR_W1SW  2048
#define PR_W2SW  2048
#define PR_W3SW  256
#define PR_WTB   64
#define PR_W5B   48
#define PR_COPY4 75000
#define PR_TOTAL (PR_W0SW + PR_W1SW + PR_W2SW + PR_W3SW + PR_WTB + PR_W5B + PR_COPY4)

#define LGKM0() asm volatile("s_waitcnt lgkmcnt(0)" ::: "memory")

__device__ __forceinline__ void gload_lds16(const void* g, void* l) {
    __builtin_amdgcn_global_load_lds(
        (const __attribute__((address_space(1))) void*)g,
        (__attribute__((address_space(3))) void*)l, 16, 0, 0);
}

__global__ __launch_bounds__(256) void prep_kernel(
    const float* __restrict__ W0, const float* __restrict__ W1,
    const float* __restrict__ W2, const float* __restrict__ W3,
    const float* __restrict__ answer, const float* __restrict__ tvec,
    const float* __restrict__ b0,
    bf16* __restrict__ W0sw, bf16* __restrict__ W1sw, bf16* __restrict__ W2sw,
    bf16* __restrict__ W3sw, bf16* __restrict__ WtB, bf16* __restrict__ W5B,
    float* __restrict__ out)
{
    int idx = blockIdx.x * 256 + threadIdx.x;
    if (idx < PR_W0SW) {                 // one chunk-lane per thread: 8 elems
        int lane = idx & 63, c = idx >> 6;
        int fr = lane & 15, quad = lane >> 4;
        int kc = c & 15, iwv = c >> 4;
        bf16 v[8];
        #pragma unroll
        for (int j = 0; j < 8; ++j)
            v[j] = (bf16)W0[(kc * 32 + quad * 8 + j) * 128 + iwv * 16 + fr];
        *(bf16x8*)(W0sw + c * 512 + lane * 8) = *(const bf16x8*)v;
        return;
    }
    idx -= PR_W0SW;
    if (idx < PR_W1SW) {
        int lane = idx & 63, c = idx >> 6;
        int fr = lane & 15, quad = lane >> 4;
        int kc = c & 3, nt = c >> 2;
        bf16 v[8];
        #pragma unroll
        for (int j = 0; j < 8; ++j)
            v[j] = (bf16)W1[(kc * 32 + quad * 8 + j) * 128 + nt * 16 + fr];
        *(bf16x8*)(W1sw + c * 512 + lane * 8) = *(const bf16x8*)v;
        return;
    }
    idx -= PR_W1SW;
    if (idx < PR_W2SW) {
        int lane = idx & 63, c = idx >> 6;
        int fr = lane & 15, quad = lane >> 4;
        int kc = c & 3, nt = c >> 2;
        bf16 v[8];
        #pragma unroll
        for (int j = 0; j < 8; ++j)
            v[j] = (bf16)W2[(kc * 32 + quad * 8 + j) * 128 + nt * 16 + fr];
        *(bf16x8*)(W2sw + c * 512 + lane * 8) = *(const bf16x8*)v;
        return;
    }
    idx -= PR_W2SW;
    if (idx < PR_W3SW) {
        int lane = idx & 63, kc = idx >> 6;
        int fr = lane & 15, quad = lane >> 4;
        bf16 v[8];
        #pragma unroll
        for (int j = 0; j < 8; ++j)
            v[j] = (fr < 2) ? (bf16)W3[(kc * 32 + quad * 8 + j) * 2 + fr] : (bf16)0.0f;
        *(bf16x8*)(W3sw + kc * 512 + lane * 8) = *(const bf16x8*)v;
        return;
    }
    idx -= PR_W3SW;
    if (idx < PR_WTB) {                 // Wt[t][j] = tvec[t]*W0[512][j] + b0[j]
        int t = idx >> 4, s = idx & 15;
        float tv = tvec[t];
        bf16 v[8];
        #pragma unroll
        for (int j = 0; j < 8; ++j)
            v[j] = (bf16)(tv * W0[512 * 128 + s * 8 + j] + b0[s * 8 + j]);
        *(bf16x8*)(WtB + t * 128 + s * 8) = *(const bf16x8*)v;
        return;
    }
    idx -= PR_WTB;
    if (idx < PR_W5B) {                 // W0 rows 513,514,515 -> bf16
        int r = idx >> 4, s = idx & 15;
        bf16 v[8];
        #pragma unroll
        for (int j = 0; j < 8; ++j)
            v[j] = (bf16)W0[(513 + r) * 128 + s * 8 + j];
        *(bf16x8*)(W5B + r * 128 + s * 8) = *(const bf16x8*)v;
        return;
    }
    idx -= PR_W5B;
    if (idx < PR_COPY4) { ((float4*)out)[idx] = ((const float4*)answer)[idx]; }
}

// E_i[n][j] = sum_k enc[n][k]*W0[i*128+k][j]. 256-thread / 64-row blocks.
__global__ __launch_bounds__(256) void prep_e_kernel(
    const float* __restrict__ encoded, const bf16* __restrict__ W0sw,
    bf16* __restrict__ E)
{
    __shared__ bf16 sA[64][136];
    __shared__ bf16 sT[64][40];
    const int tid = threadIdx.x;
    const int row0 = (blockIdx.x >> 2) * 64;
    const int ntb  = blockIdx.x & 3;
    for (int c = tid; c < 2048; c += 256) {      // 64 rows x 32 float4
        int row = c >> 5, seg = c & 31;
        int rr = row0 + row; if (rr >= NN) rr = NN - 1;
        float4 v = *(const float4*)(encoded + (size_t)rr * 128 + seg * 4);
        bf16 pk[4] = {(bf16)v.x, (bf16)v.y, (bf16)v.z, (bf16)v.w};
        *(uint2*)(&sA[row][seg * 4]) = *(const uint2*)pk;
    }
    __syncthreads();                             // sA staged (cross-wave)
    const int wv = tid >> 6, lane = tid & 63;
    const int fr = lane & 15, quad = lane >> 4;
    const bf16* aBase = &sA[wv * 16 + fr][quad * 8];
    bf16x8 aFv[4];
    #pragma unroll
    for (int kcc = 0; kcc < 4; ++kcc) aFv[kcc] = *(const bf16x8*)(aBase + kcc * 32);
    const int orow = tid >> 2, oseg = tid & 3;
    #pragma unroll
    for (int i = 0; i < 4; ++i) {
        #pragma unroll
        for (int ntl = 0; ntl < 2; ++ntl) {
            int nt = ntb * 2 + ntl;
            f32x4 acc = {0.f, 0.f, 0.f, 0.f};
            #pragma unroll
            for (int kcc = 0; kcc < 4; ++kcc) {
                bf16x8 bF = *(const bf16x8*)(W0sw + ((size_t)nt * 16 + i * 4 + kcc) * 512 + lane * 8);
                acc = __builtin_amdgcn_mfma_f32_16x16x32_bf16(aFv[kcc], bF, acc, 0, 0, 0);
            }
            #pragma unroll
            for (int reg = 0; reg < 4; ++reg)
                sT[wv * 16 + quad * 4 + reg][ntl * 16 + fr] = (bf16)acc[reg];
        }
        LGKM0();                                 // own sT writes visible to own wave
        bf16x8 ev = *(const bf16x8*)(&sT[orow][oseg * 8]);
        LGKM0();                                 // reads retired before next i's overwrite
        if (row0 + orow < NN)
            *(bf16x8*)(E + ((size_t)i * NN + row0 + orow) * 128 + ntb * 32 + oseg * 8) = ev;
    }
}

// ---------------------------------------------------------------------------
// Main kernel, R21 (resubmitted after infra failure — identical source).
// M=32/wave: 4 waves x 8 propers (2 M-tiles of 16 rows) per block, full
// N=128 per wave. Every B-frag ds_read_b128 feeds 2 MFMAs — halves the
// dominant LDS-read cost per row (theory: LDS issue pipe is the hidden
// bound; R18 counted ~59 us of DS-op issue in the 74 us kernel).
// R20's LDS offset bug fixed: two-phase staging puts W2 at byte 0
// (overwriting W1) and W3 at byte 32768 — layer 2 reads OFFW=0, delta
// reads sW+16384 (bf16 units).
// ---------------------------------------------------------------------------
__global__ __launch_bounds__(256, 2) void main_kernel(
    const float* __restrict__ coords, const int* __restrict__ propers,
    const float* __restrict__ b1, const float* __restrict__ b2,
    const float* __restrict__ b3,
    const bf16* __restrict__ E, const bf16* __restrict__ W1sw,
    const bf16* __restrict__ W2sw, const bf16* __restrict__ W3sw,
    const bf16* __restrict__ WtB, const bf16* __restrict__ W5B,
    float* __restrict__ out)
{
    __shared__ __align__(16) bf16 sH[WPB][RPW][136];  // per-wave 32-row tile
    __shared__ __align__(16) bf16 sW[18432];          // 32KB W1/W2 @0 + 4KB W3 @16384
    __shared__ float sScr[WPB][RPW][6];               // [0..2]=dh, [3..4]=delta
    __shared__ int   sNd[WPB][16];                    // {n0,n3} x 8 propers

    const int tid  = threadIdx.x;
    const int wv   = tid >> 6, lane = tid & 63;
    const int fr   = lane & 15, quad = lane >> 4;
    const int pw   = blockIdx.x * PB + wv * PPW;      // first proper of wave

    // ---- stage W1 (32KB @ byte 0) + W3 (4KB @ byte 32768), async ----
    {
        const char* g1 = (const char*)W1sw;
        #pragma unroll
        for (int r8 = 0; r8 < 8; ++r8)
            gload_lds16(g1 + (size_t)(r8 * WPB + wv) * 1024 + lane * 16,
                        (char*)sW + (r8 * WPB + wv) * 1024);
        gload_lds16((const char*)W3sw + (size_t)wv * 1024 + lane * 16,
                    (char*)sW + 32768 + wv * 1024);
    }

    // ---- E gather, two passes: pass A propers pw+quad, pass B pw+4+quad ----
    int4 pvA = *(const int4*)(propers + (size_t)(pw + quad) * 4);
    int4 pvB = *(const int4*)(propers + (size_t)(pw + 4 + quad) * 4);
    bf16x8 e0a = *(const bf16x8*)(E + ((size_t)0 * NN + pvA.x) * 128 + fr * 8);
    bf16x8 e1a = *(const bf16x8*)(E + ((size_t)1 * NN + pvA.y) * 128 + fr * 8);
    bf16x8 e2a = *(const bf16x8*)(E + ((size_t)2 * NN + pvA.z) * 128 + fr * 8);
    bf16x8 e3a = *(const bf16x8*)(E + ((size_t)3 * NN + pvA.w) * 128 + fr * 8);
    bf16x8 e0b = *(const bf16x8*)(E + ((size_t)0 * NN + pvB.x) * 128 + fr * 8);
    bf16x8 e1b = *(const bf16x8*)(E + ((size_t)1 * NN + pvB.y) * 128 + fr * 8);
    bf16x8 e2b = *(const bf16x8*)(E + ((size_t)2 * NN + pvB.z) * 128 + fr * 8);
    bf16x8 e3b = *(const bf16x8*)(E + ((size_t)3 * NN + pvB.w) * 128 + fr * 8);
    if (fr == 0) {
        sNd[wv][quad * 2]     = pvA.x; sNd[wv][quad * 2 + 1]     = pvA.w;
        sNd[wv][8 + quad * 2] = pvB.x; sNd[wv][8 + quad * 2 + 1] = pvB.w;
    }
    bf16x8 w3v = *(const bf16x8*)(W5B + 0 * 128 + fr * 8);
    bf16x8 w4v = *(const bf16x8*)(W5B + 1 * 128 + fr * 8);
    bf16x8 w5v = *(const bf16x8*)(W5B + 2 * 128 + fr * 8);
    bf16x8 wtv[4];
    #pragma unroll
    for (int t = 0; t < 4; ++t) wtv[t] = *(const bf16x8*)(WtB + t * 128 + fr * 8);

    // ---- bias preload ----
    float b1r[8], b2r[8];
    #pragma unroll
    for (int i = 0; i < 8; ++i) {
        b1r[i] = b1[i * 16 + fr];
        b2r[i] = b2[i * 16 + fr];
    }
    float b3r = (fr < 2) ? b3[fr] : 0.0f;

    // ---- geometry: lanes 0..31 each own one of the wave's 32 rows ----
    float snl = 0.f, csl = 1.f, dll = 0.f;
    if (lane < 32) {
        int pp_ = lane >> 2, t = lane & 3;
        int4 pg = *(const int4*)(propers + (size_t)(pw + pp_) * 4);
        const float* c0 = coords + (size_t)pg.x * 12 + t * 3;
        const float* c1 = coords + (size_t)pg.y * 12 + t * 3;
        const float* c2 = coords + (size_t)pg.z * 12 + t * 3;
        const float* c3 = coords + (size_t)pg.w * 12 + t * 3;
        float u1x = c1[0]-c0[0], u1y = c1[1]-c0[1], u1z = c1[2]-c0[2];
        float u2x = c2[0]-c1[0], u2y = c2[1]-c1[1], u2z = c2[2]-c1[2];
        float u3x = c3[0]-c2[0], u3y = c3[1]-c2[1], u3z = c3[2]-c2[2];
        float ax = u1y*u2z - u1z*u2y, ay = u1z*u2x - u1x*u2z, az = u1x*u2y - u1y*u2x;
        float bx = u2y*u3z - u2z*u3y, by = u2z*u3x - u2x*u3z, bz = u2x*u3y - u2y*u3x;
        float u2n = sqrtf(u2x*u2x + u2y*u2y + u2z*u2z);
        float num = u2n * (u1x*bx + u1y*by + u1z*bz);
        float den = ax*bx + ay*by + az*bz;
        float hyp = sqrtf(num*num + den*den);
        if (hyp > 1e-30f) { float ih = 1.0f / hyp; snl = num * ih; csl = den * ih; }
        else { snl = 0.0f; csl = 1.0f; }
        float drx = c0[0]-c3[0], dry = c0[1]-c3[1], drz = c0[2]-c3[2];
        dll = sqrtf(fmaxf(drx*drx + dry*dry + drz*drz, 1e-12f));
        float il = 1.0f / dll;
        sScr[wv][lane][0] = drx * il;
        sScr[wv][lane][1] = dry * il;
        sScr[wv][lane][2] = drz * il;
    }

    // ---- h0 (two passes, packed f32x2 math) -> sH[wv] ----
    {
        f32x2 w3f2[4], w4f2[4], w5f2[4];
        #pragma unroll
        for (int j = 0; j < 4; ++j) {
            w3f2[j] = (f32x2){ (float)w3v[2*j], (float)w3v[2*j+1] };
            w4f2[j] = (f32x2){ (float)w4v[2*j], (float)w4v[2*j+1] };
            w5f2[j] = (f32x2){ (float)w5v[2*j], (float)w5v[2*j+1] };
        }
#define H0_PASS(E0, E1, E2, E3, RBASE)                                          \
        {                                                                       \
            f32x2 g2[4];                                                        \
            _Pragma("unroll")                                                   \
            for (int j = 0; j < 4; ++j)                                         \
                g2[j] = (f32x2){                                                \
                    (float)E0[2*j]   + (float)E1[2*j]   + (float)E2[2*j]   + (float)E3[2*j],   \
                    (float)E0[2*j+1] + (float)E1[2*j+1] + (float)E2[2*j+1] + (float)E3[2*j+1] };\
            _Pragma("unroll")                                                   \
            for (int t = 0; t < 4; ++t) {                                       \
                int r = (RBASE) + quad * 4 + t;                                 \
                float sn = __shfl(snl, r), cs = __shfl(csl, r), dl = __shfl(dll, r); \
                f32x2 sn2 = {sn, sn}, cs2 = {cs, cs}, dl2 = {dl, dl};           \
                bf16 hv[8];                                                     \
                _Pragma("unroll")                                               \
                for (int j = 0; j < 4; ++j) {                                   \
                    f32x2 v = g2[j] + (f32x2){ (float)wtv[t][2*j], (float)wtv[t][2*j+1] }; \
                    v = sn2 * w3f2[j] + v;                                      \
                    v = cs2 * w4f2[j] + v;                                      \
                    v = dl2 * w5f2[j] + v;                                      \
                    f32x2 lv = v * LEAKY;                                       \
                    v.x = fmaxf(v.x, lv.x);                                     \
                    v.y = fmaxf(v.y, lv.y);                                     \
                    hv[2*j]   = (bf16)v.x;                                      \
                    hv[2*j+1] = (bf16)v.y;                                      \
                }                                                               \
                *(bf16x8*)(&sH[wv][r][fr * 8]) = *(const bf16x8*)hv;            \
            }                                                                   \
        }
        H0_PASS(e0a, e1a, e2a, e3a, 0)
        H0_PASS(e0b, e1b, e2b, e3b, 16)
#undef H0_PASS
    }
    __syncthreads();   // B1: W1+W3 staged (vmcnt drained); h0 ready (wave-local)

    // ---- dense layer: 2 M-tiles share every B-frag read (the R20 lever) ----
#define DENSE_LAYER(OFFW, BR)                                                   \
    {                                                                           \
        bf16x8 aF[2][4];                                                        \
        _Pragma("unroll")                                                       \
        for (int mt = 0; mt < 2; ++mt) {                                        \
            const bf16* aRow = &sH[wv][mt * 16 + fr][quad * 8];                 \
            _Pragma("unroll")                                                   \
            for (int kc = 0; kc < 4; ++kc)                                      \
                aF[mt][kc] = *(const bf16x8*)(aRow + kc * 32);                  \
        }                                                                       \
        _Pragma("unroll")                                                       \
        for (int hh = 0; hh < 2; ++hh) {                                        \
            f32x4 acc[2][4];                                                    \
            _Pragma("unroll")                                                   \
            for (int mt = 0; mt < 2; ++mt)                                      \
                _Pragma("unroll")                                               \
                for (int nt = 0; nt < 4; ++nt) acc[mt][nt] = (f32x4){0.f,0.f,0.f,0.f}; \
            __builtin_amdgcn_s_setprio(1);                                      \
            _Pragma("unroll")                                                   \
            for (int kc = 0; kc < 4; ++kc) {                                    \
                _Pragma("unroll")                                               \
                for (int nt = 0; nt < 4; ++nt) {                                \
                    bf16x8 bF = *(const bf16x8*)(sW + OFFW +                    \
                        ((hh * 4 + nt) * 4 + kc) * 512 + lane * 8);             \
                    acc[0][nt] = __builtin_amdgcn_mfma_f32_16x16x32_bf16(       \
                        aF[0][kc], bF, acc[0][nt], 0, 0, 0);                    \
                    acc[1][nt] = __builtin_amdgcn_mfma_f32_16x16x32_bf16(       \
                        aF[1][kc], bF, acc[1][nt], 0, 0, 0);                    \
                }                                                               \
            }                                                                   \
            __builtin_amdgcn_s_setprio(0);                                      \
            _Pragma("unroll")                                                   \
            for (int mt = 0; mt < 2; ++mt)                                      \
                _Pragma("unroll")                                               \
                for (int nt = 0; nt < 4; ++nt) {                                \
                    int j = (hh * 4 + nt) * 16 + fr;                            \
                    f32x4 v = acc[mt][nt] + BR[hh * 4 + nt];                    \
                    f32x4 lv = v * LEAKY;                                       \
                    v.x = fmaxf(v.x, lv.x); v.y = fmaxf(v.y, lv.y);             \
                    v.z = fmaxf(v.z, lv.z); v.w = fmaxf(v.w, lv.w);             \
                    _Pragma("unroll")                                           \
                    for (int reg = 0; reg < 4; ++reg)                           \
                        sH[wv][mt * 16 + quad * 4 + reg][j] = (bf16)v[reg];     \
                }                                                               \
        }                                                                       \
    }

    DENSE_LAYER(0, b1r)        // h1 = leaky(h0 @ W1 + b1), in place
    __syncthreads();           // B2: all waves done reading W1 frags
    {                          // stage W2 over W1 at byte 0 (async, drained at B3)
        const char* g2 = (const char*)W2sw;
        #pragma unroll
        for (int r8 = 0; r8 < 8; ++r8)
            gload_lds16(g2 + (size_t)(r8 * WPB + wv) * 1024 + lane * 16,
                        (char*)sW + (r8 * WPB + wv) * 1024);
    }
    __syncthreads();           // B3: W2 staged
    DENSE_LAYER(0, b2r)        // h2 = leaky(h1 @ W2 + b2) — W2 lives at offset 0

    // ---- delta = h2 @ W3 + b3; W3 frags at bf16-offset 16384 (byte 32768) ----
    {
        bf16x8 bW[4];
        #pragma unroll
        for (int kc = 0; kc < 4; ++kc)
            bW[kc] = *(const bf16x8*)(sW + 16384 + kc * 512 + lane * 8);
        #pragma unroll
        for (int mt = 0; mt < 2; ++mt) {
            bf16x8 aF[4];
            const bf16* aRow = &sH[wv][mt * 16 + fr][quad * 8];
            #pragma unroll
            for (int kc = 0; kc < 4; ++kc)
                aF[kc] = *(const bf16x8*)(aRow + kc * 32);
            f32x4 dacc = {0.f, 0.f, 0.f, 0.f};
            __builtin_amdgcn_s_setprio(1);
            #pragma unroll
            for (int kc = 0; kc < 4; ++kc)
                dacc = __builtin_amdgcn_mfma_f32_16x16x32_bf16(aF[kc], bW[kc], dacc, 0, 0, 0);
            __builtin_amdgcn_s_setprio(0);
            if (fr < 2) {
                #pragma unroll
                for (int reg = 0; reg < 4; ++reg)
                    sScr[wv][mt * 16 + quad * 4 + reg][3 + fr] = dacc[reg] + b3r;
            }
        }
    }

    // ---- scatter: 32 rows x 2 sides; lane = row + 32*side; 3 atomics each ----
    {
        int row  = lane & 31;
        int side = lane >> 5;
        int node = sNd[wv][(row >> 2) * 2 + side];
        float dval = (side ? 0.5f : -0.5f) * sScr[wv][row][3 + side];
        float* op = out + (size_t)node * 12 + (row & 3) * 3;
        #pragma unroll
        for (int ax = 0; ax < 3; ++ax)
            atomicAdd(op + ax, dval * sScr[wv][row][ax]);
    }
#undef DENSE_LAYER
}

extern "C" void kernel_launch(void* const* d_in, const int* in_sizes, int n_in,
                              void* d_out, int out_size, void* d_ws, size_t ws_size,
                              hipStream_t stream) {
    const float* coords  = (const float*)d_in[0];
    const int*   propers = (const int*)d_in[1];
    const float* encoded = (const float*)d_in[2];
    const float* tvec    = (const float*)d_in[3];
    const float* answer  = (const float*)d_in[4];
    const float* W0 = (const float*)d_in[5];
    const float* b0 = (const float*)d_in[6];
    const float* W1 = (const float*)d_in[7];
    const float* b1 = (const float*)d_in[8];
    const float* W2 = (const float*)d_in[9];
    const float* b2 = (const float*)d_in[10];
    const float* W3 = (const float*)d_in[11];
    const float* b3 = (const float*)d_in[12];
    float* out = (float*)d_out;
    char* ws = (char*)d_ws;
    bf16* W0sw = (bf16*)(ws + OFF_W0SW);
    bf16* W1sw = (bf16*)(ws + OFF_W1SW);
    bf16* W2sw = (bf16*)(ws + OFF_W2SW);
    bf16* W3sw = (bf16*)(ws + OFF_W3SW);
    bf16* WtB  = (bf16*)(ws + OFF_WTB);
    bf16* W5B  = (bf16*)(ws + OFF_W5B);
    bf16* E    = (bf16*)(ws + OFF_E);

    int prep_blocks = (PR_TOTAL + 255) / 256;
    prep_kernel<<<prep_blocks, 256, 0, stream>>>(W0, W1, W2, W3, answer, tvec, b0,
                                                 W0sw, W1sw, W2sw, W3sw, WtB, W5B, out);
    prep_e_kernel<<<391 * 4, 256, 0, stream>>>(encoded, W0sw, E);
    main_kernel<<<PP / PB, 256, 0, stream>>>(coords, propers, b1, b2, b3,
                                             E, W1sw, W2sw, W3sw, WtB, W5B, out);
}